// Round 3
// baseline (2257.044 us; speedup 1.0000x reference)
//
#include <hip/hip_runtime.h>
#include <hip/hip_bf16.h>

typedef unsigned short u16;
typedef unsigned int   u32;
typedef __bf16 bf16x8 __attribute__((ext_vector_type(8)));
typedef float  f32x4  __attribute__((ext_vector_type(4)));
typedef float  f32x2  __attribute__((ext_vector_type(2)));
typedef u32    u32x4  __attribute__((ext_vector_type(4)));

#define AS1 __attribute__((address_space(1)))
#define AS3 __attribute__((address_space(3)))

__device__ __forceinline__ u16 f2bf(float f){
    u32 u = __float_as_uint(f);
    u32 r = u + 0x7fffu + ((u>>16)&1u);
    return (u16)(r>>16);
}
__device__ __forceinline__ void up2(u32 p, float& a, float& b){
    a = __uint_as_float(p<<16);
    b = __uint_as_float(p & 0xffff0000u);
}
// pack two fp32 -> two bf16 (truncation; bias cancels in symmetric dots)
__device__ __forceinline__ u32 pack_bf(float a, float b){
    return (__float_as_uint(a)>>16) | (__float_as_uint(b) & 0xffff0000u);
}

// ---------------- degree ----------------
__global__ void k_deg(const int* __restrict__ dst, float* __restrict__ degb, int E){
    int e = blockIdx.x*256 + threadIdx.x;
    if (e < E) atomicAdd(&degb[dst[e]], 1.0f);
}

// degb -> invdeg in place; rw0 = degc^2 (so rw0*invdeg = degc = RWSE col 0)
__global__ void k_degc(float* __restrict__ invdeg, float* __restrict__ rw0, int n){
    int v = blockIdx.x*256 + threadIdx.x;
    if (v < n){
        float c = invdeg[v];
        if (c == 0.f) c = 1.f;
        invdeg[v] = 1.f/c;
        rw0[v] = c*c;
    }
}

// raw_{t+1}[dst] += (raw_t[src] * invdeg[src])
__global__ void k_rwse(const float* __restrict__ cur, float* __restrict__ nxt,
                       const float* __restrict__ invdeg, const int* __restrict__ src,
                       const int* __restrict__ dst, int E){
    int e = blockIdx.x*256 + threadIdx.x;
    if (e < E){
        int s = src[e];
        atomicAdd(&nxt[dst[e]], cur[s]*invdeg[s]);
    }
}

// out0 = relu([n_feat, rwse] @ lin0_w + lin0_b)   (all fp32)
__global__ void k_finalize(const float* __restrict__ nfeat, const float* __restrict__ rw,
                           const float* __restrict__ invdeg,
                           const float* __restrict__ lw, const float* __restrict__ lb,
                           float* __restrict__ out0, int n){
    __shared__ float lwl[1024];
    __shared__ float lbl[32];
    __shared__ float nfl[8][32];
    int tid = threadIdx.x;
    for (int i = tid; i < 1024; i += 256) lwl[i] = lw[i];
    if (tid < 32) lbl[tid] = lb[tid];
    int slot = tid>>5, o = tid&31;
    int v = blockIdx.x*8 + slot;
    float nfv = 0.f;
    if (v < n){
        nfv = (o < 16) ? nfeat[(size_t)v*16 + o]
                       : rw[(size_t)(o-16)*n + v]*invdeg[v];
    }
    nfl[slot][o] = nfv;
    __syncthreads();
    if (v < n){
        float a = lbl[o];
        #pragma unroll
        for (int j = 0; j < 32; j++) a += nfl[slot][j]*lwl[j*32+o];
        out0[(size_t)v*32 + o] = a > 0.f ? a : 0.f;
    }
}

// WT[n*1024+k] = bf16(w[k*1024+n])  (fp32 -> bf16, 1024x1024)
__global__ void k_transpose(const float* __restrict__ w, u16* __restrict__ wt){
    __shared__ float t[32][33];
    int bx = blockIdx.x & 31, by = blockIdx.x >> 5;
    int x = threadIdx.x & 31, y = threadIdx.x >> 5;
    #pragma unroll
    for (int i = 0; i < 32; i += 8)
        t[y+i][x] = w[(size_t)(by*32 + y + i)*1024 + bx*32 + x];
    __syncthreads();
    #pragma unroll
    for (int i = 0; i < 32; i += 8)
        wt[(size_t)(bx*32 + y + i)*1024 + by*32 + x] = f2bf(t[x][y+i]);
}

// gate[e] = sigmoid(e_feat[e] . gw + gb)   one wave per edge
__global__ void k_gate(const float* __restrict__ ef, const float* __restrict__ gw,
                       const float* __restrict__ gb, float* __restrict__ gate, int E)
{
    __shared__ float gwl[1024];
    int tid = threadIdx.x;
    for (int i = tid; i < 1024; i += 256) gwl[i] = gw[i];
    __syncthreads();
    int wave = tid>>6, lane = tid&63;
    int e = blockIdx.x*4 + wave;
    if (e >= E) return;
    const f32x4* ep = (const f32x4*)(ef + (size_t)e*1024);
    float acc = 0.f;
    #pragma unroll
    for (int j = 0; j < 4; j++){
        int idx = j*64 + lane;
        f32x4 c = ep[idx];
        const float* g = &gwl[idx*4];
        acc += c.x*g[0] + c.y*g[1] + c.z*g[2] + c.w*g[3];
    }
    #pragma unroll
    for (int m = 32; m >= 1; m >>= 1) acc += __shfl_xor(acc, m, 64);
    if (lane == 0) gate[e] = 1.f/(1.f + __expf(-(acc + gb[0])));
}

// P = relu(A @ B + bias) * gate; store per-edge transposed [o][h]
// A fp32 (staged via global_load_lds, packed to bf16 in-reg), B bf16 (pre-transposed)
// FP8==0: bf16 store; FP8==1: e4m3 store
template<int FP8>
__global__ __launch_bounds__(256) void k_gemm(
    const float* __restrict__ A, const u16* __restrict__ BT,
    const float* __restrict__ bias, const float* __restrict__ gate,
    void* __restrict__ WoutV, int E)
{
    __shared__ __align__(16) float lds_a[128*32];  // [kq][m] chunks of 4 floats
    __shared__ __align__(16) u16   lds_b[128*32];  // [q][n]  chunks of 8 bf16

    const int tid  = threadIdx.x;
    const int wave = tid>>6, lane = tid&63;
    const int wm = wave>>1, wn = wave&1;
    const int ql = lane>>4, rl = lane&15;
    const int mb = blockIdx.x>>3, nb = blockIdx.x&7;
    const int m0 = mb<<7, n0 = nb<<7;

    f32x4 acc[4][4];
    #pragma unroll
    for (int i=0;i<4;i++)
    #pragma unroll
        for (int j=0;j<4;j++) acc[i][j] = (f32x4){0.f,0.f,0.f,0.f};

    for (int k0 = 0; k0 < 1024; k0 += 32){
        __syncthreads();
        // A: fp32, 1024 chunks of 16B; ci -> (m = ci&127, kq = ci>>7)
        #pragma unroll
        for (int j=0;j<4;j++){
            const int cb = j*256 + wave*64;        // wave-uniform
            const int ci = cb + lane;
            const int m  = ci & 127, kq = ci >> 7;
            int row = m0 + m; if (row >= E) row = E-1;
            const float* ga = A + (size_t)row*1024 + k0 + kq*4;
            __builtin_amdgcn_global_load_lds(
                (const AS1 void*)ga, (AS3 void*)&lds_a[cb*4], 16, 0, 0);
        }
        // B: bf16, 512 chunks of 16B; ci -> (n = ci&127, q = ci>>7)
        #pragma unroll
        for (int j=0;j<2;j++){
            const int cb = (j*4 + wave)*64;        // wave-uniform
            const int ci = cb + lane;
            const int n  = ci & 127, q = ci >> 7;
            const u16* gB = BT + (size_t)(n0 + n)*1024 + (k0 + q*8);
            __builtin_amdgcn_global_load_lds(
                (const AS1 void*)gB, (AS3 void*)&lds_b[cb*8], 16, 0, 0);
        }
        __syncthreads();

        bf16x8 af[4], bfr[4];
        #pragma unroll
        for (int t=0;t<4;t++){
            const int m = wm*64 + t*16 + rl;
            f32x4 lo = *(const f32x4*)&lds_a[((ql*2    )*128 + m)*4];
            f32x4 hi = *(const f32x4*)&lds_a[((ql*2 + 1)*128 + m)*4];
            u32x4 pk = { pack_bf(lo.x, lo.y), pack_bf(lo.z, lo.w),
                         pack_bf(hi.x, hi.y), pack_bf(hi.z, hi.w) };
            af[t]  = __builtin_bit_cast(bf16x8, pk);
            bfr[t] = *(const bf16x8*)&lds_b[(ql*128 + wn*64 + t*16 + rl)*8];
        }
        #pragma unroll
        for (int mt=0;mt<4;mt++)
        #pragma unroll
            for (int nt=0;nt<4;nt++)
                acc[mt][nt] = __builtin_amdgcn_mfma_f32_16x16x32_bf16(af[mt], bfr[nt], acc[mt][nt], 0,0,0);
    }

    if (FP8 == 0){
        u16* Wout = (u16*)WoutV;
        #pragma unroll
        for (int nt=0;nt<4;nt++){
            const int col = n0 + wn*64 + nt*16 + rl;
            const float bcol = bias[col];
            const int coff = ((col & 31) << 5) + (col >> 5);   // [o][h]
            #pragma unroll
            for (int mt=0;mt<4;mt++){
                const int rloc0 = wm*64 + mt*16 + ql*4;
                #pragma unroll
                for (int r=0;r<4;r++){
                    const int row = m0 + rloc0 + r;
                    if (row < E){
                        float v = acc[mt][nt][r] + bcol;
                        v = v > 0.f ? v : 0.f;
                        v *= gate[row];
                        Wout[(size_t)row*1024 + coff] = f2bf(v);
                    }
                }
            }
        }
    } else {
        u16* W8 = (u16*)WoutV;    // 2 fp8 per u16, layout [o][h], h pairs
        #pragma unroll
        for (int pp=0;pp<2;pp++){
            const int colA = n0 + wn*64 + pp*16 + rl;
            const int colB = colA + 32;
            const float bA = bias[colA];
            const float bB = bias[colB];
            const int o  = colA & 31;
            const int hb = colA >> 5;          // even
            const int widx = o*16 + (hb>>1);
            #pragma unroll
            for (int mt=0;mt<4;mt++){
                const int rloc0 = wm*64 + mt*16 + ql*4;
                #pragma unroll
                for (int r=0;r<4;r++){
                    const int row = m0 + rloc0 + r;
                    if (row < E){
                        const float g = gate[row];
                        float va = acc[mt][pp][r]   + bA; va = va>0.f?va:0.f; va *= g;
                        float vb = acc[mt][pp+2][r] + bB; vb = vb>0.f?vb:0.f; vb *= g;
                        u32 p = (u32)__builtin_amdgcn_cvt_pk_fp8_f32(va, vb, 0, false);
                        W8[(size_t)row*512 + widx] = (u16)(p & 0xffffu);
                    }
                }
            }
        }
    }
}

// msg[e][o] = sum_h out[src[e]][h] * W[e][h][o]; atomic into neigh[dst]
template<int FP8>
__global__ void k_msg(const float* __restrict__ outc, const void* __restrict__ WtV,
                      const int* __restrict__ src, const int* __restrict__ dst,
                      float* __restrict__ neigh, int E)
{
    __shared__ float xl[8][32];
    const int tid = threadIdx.x, slot = tid>>5, o = tid&31;
    const int e = blockIdx.x*8 + slot;
    int d = 0;
    if (e < E){
        d = dst[e];
        xl[slot][o] = outc[(size_t)src[e]*32 + o];
    }
    __syncthreads();
    if (e < E){
        const float* x = xl[slot];
        float acc = 0.f;
        if (FP8 == 0){
            const uint4* wp = (const uint4*)((const u16*)WtV + (size_t)e*1024 + o*32);
            #pragma unroll
            for (int q=0;q<4;q++){
                uint4 c = wp[q];
                float a0,a1;
                up2(c.x,a0,a1); acc += x[q*8+0]*a0 + x[q*8+1]*a1;
                up2(c.y,a0,a1); acc += x[q*8+2]*a0 + x[q*8+3]*a1;
                up2(c.z,a0,a1); acc += x[q*8+4]*a0 + x[q*8+5]*a1;
                up2(c.w,a0,a1); acc += x[q*8+6]*a0 + x[q*8+7]*a1;
            }
        } else {
            const u32* wp = (const u32*)((const unsigned char*)WtV + (size_t)e*1024 + o*32);
            #pragma unroll
            for (int q=0;q<8;q++){
                u32 c = wp[q];
                f32x2 lo = __builtin_amdgcn_cvt_pk_f32_fp8(c, false);
                f32x2 hi = __builtin_amdgcn_cvt_pk_f32_fp8(c, true);
                acc += x[q*4+0]*lo.x + x[q*4+1]*lo.y + x[q*4+2]*hi.x + x[q*4+3]*hi.y;
            }
        }
        atomicAdd(&neigh[(size_t)d*32 + o], acc);
    }
}

// m = relu(neigh*invdeg + out + cb); out_new = [m,out] @ mw + mb   (fp32)
__global__ void k_node(const float* __restrict__ neigh, const float* __restrict__ invdeg,
                       const float* __restrict__ outc, const float* __restrict__ cb,
                       const float* __restrict__ mw, const float* __restrict__ mb,
                       float* __restrict__ outn, int n)
{
    __shared__ float mwl[2048];
    __shared__ float cat[8][64];
    int tid = threadIdx.x;
    for (int i = tid; i < 2048; i += 256) mwl[i] = mw[i];
    int slot = tid>>5, o = tid&31;
    int v = blockIdx.x*8 + slot;
    if (v < n){
        float ov = outc[(size_t)v*32 + o];
        float m = neigh[(size_t)v*32 + o]*invdeg[v] + ov + cb[o];
        m = m > 0.f ? m : 0.f;
        cat[slot][o] = m;
        cat[slot][32+o] = ov;
    }
    __syncthreads();
    if (v < n){
        float a = mb[o];
        #pragma unroll
        for (int j = 0; j < 64; j++) a += cat[slot][j]*mwl[j*32+o];
        outn[(size_t)v*32 + o] = a;
    }
}

__global__ void k_group(const float* __restrict__ outc, const int* __restrict__ src,
                        const int* __restrict__ dst, float* __restrict__ grp, int E)
{
    int tid = threadIdx.x, slot = tid>>5, o = tid&31;
    int e = blockIdx.x*8 + slot;
    if (e < E)
        atomicAdd(&grp[(size_t)dst[e]*32 + o], outc[(size_t)src[e]*32 + o]);
}

// out_final = [out, group*invdeg] @ sw + sb + init  (fp32 out)
// init recomputed on the fly: [n_feat | rw*invdeg]
__global__ void k_final(const float* __restrict__ outc, const float* __restrict__ grp,
                        const float* __restrict__ invdeg, const float* __restrict__ sw,
                        const float* __restrict__ sb, const float* __restrict__ nfeat,
                        const float* __restrict__ rw,
                        float* __restrict__ dout, int n)
{
    __shared__ float swl[2048];
    __shared__ float cat[8][64];
    int tid = threadIdx.x;
    for (int i = tid; i < 2048; i += 256) swl[i] = sw[i];
    int slot = tid>>5, o = tid&31;
    int v = blockIdx.x*8 + slot;
    float iv = 0.f;
    if (v < n){
        iv = invdeg[v];
        cat[slot][o] = outc[(size_t)v*32 + o];
        cat[slot][32+o] = grp[(size_t)v*32 + o]*iv;
    }
    __syncthreads();
    if (v < n){
        float a = sb[o];
        #pragma unroll
        for (int j = 0; j < 64; j++) a += cat[slot][j]*swl[j*32+o];
        float initv = (o < 16) ? nfeat[(size_t)v*16 + o]
                               : rw[(size_t)(o-16)*n + v]*iv;
        dout[(size_t)v*32 + o] = a + initv;
    }
}

extern "C" void kernel_launch(void* const* d_in, const int* in_sizes, int n_in,
                              void* d_out, int out_size, void* d_ws, size_t ws_size,
                              hipStream_t stream)
{
    const float* n_feat = (const float*)d_in[0];
    const float* e_feat = (const float*)d_in[1];
    const int*   src    = (const int*)d_in[2];
    const int*   dst    = (const int*)d_in[3];
    const float* epw    = (const float*)d_in[4];
    const float* epb    = (const float*)d_in[5];
    const float* gw     = (const float*)d_in[6];
    const float* gb     = (const float*)d_in[7];
    const float* l0w    = (const float*)d_in[8];
    const float* l0b    = (const float*)d_in[9];
    const float* cb     = (const float*)d_in[10];
    const float* mw     = (const float*)d_in[11];
    const float* mbp    = (const float*)d_in[12];
    const float* sw     = (const float*)d_in[13];
    const float* sb     = (const float*)d_in[14];

    const int N = in_sizes[0] / 16;
    const int E = in_sizes[2];

    char* w = (char*)d_ws;
    float* invdeg = (float*)w;  w += (size_t)N*4;
    float* rw     = (float*)w;  w += (size_t)16*N*4;
    float* out_a  = (float*)w;  w += (size_t)32*N*4;
    float* out_b  = (float*)w;  w += (size_t)32*N*4;
    float* neigh  = (float*)w;  w += (size_t)32*N*4;
    float* gateb  = (float*)w;  w += (size_t)E*4;
    u16*   wtb    = (u16*)w;    w += (size_t)1024*1024*2;
    void*  wout   = (void*)w;

    const size_t base_bytes = (size_t)(w - (char*)d_ws);
    const size_t need_bf16  = base_bytes + (size_t)E*1024*2;
    const int use_fp8 = (ws_size < need_bf16) ? 1 : 0;

    hipMemsetAsync(invdeg, 0, (size_t)N*4, stream);
    hipMemsetAsync(rw, 0, (size_t)16*N*4, stream);

    const int EB  = (E + 255)/256, NB = (N + 255)/256;
    const int EB8 = (E + 7)/8,    NB8 = (N + 7)/8;

    k_deg<<<EB,256,0,stream>>>(dst, invdeg, E);
    k_degc<<<NB,256,0,stream>>>(invdeg, rw, N);
    for (int t = 0; t < 15; t++)
        k_rwse<<<EB,256,0,stream>>>(rw + (size_t)t*N, rw + (size_t)(t+1)*N, invdeg, src, dst, E);
    k_finalize<<<NB8,256,0,stream>>>(n_feat, rw, invdeg, l0w, l0b, out_a, N);

    k_transpose<<<1024,256,0,stream>>>(epw, wtb);
    k_gate<<<(E+3)/4,256,0,stream>>>(e_feat, gw, gb, gateb, E);

    const int MB = (E + 127)/128;
    if (use_fp8)
        k_gemm<1><<<MB*8,256,0,stream>>>(e_feat, wtb, epb, gateb, wout, E);
    else
        k_gemm<0><<<MB*8,256,0,stream>>>(e_feat, wtb, epb, gateb, wout, E);

    float* cur = out_a; float* nxt = out_b;
    for (int it = 0; it < 3; it++){
        hipMemsetAsync(neigh, 0, (size_t)32*N*4, stream);
        if (use_fp8)
            k_msg<1><<<EB8,256,0,stream>>>(cur, wout, src, dst, neigh, E);
        else
            k_msg<0><<<EB8,256,0,stream>>>(cur, wout, src, dst, neigh, E);
        k_node<<<NB8,256,0,stream>>>(neigh, invdeg, cur, cb, mw, mbp, nxt, N);
        float* tmp = cur; cur = nxt; nxt = tmp;
    }

    hipMemsetAsync(neigh, 0, (size_t)32*N*4, stream);
    k_group<<<EB8,256,0,stream>>>(cur, src, dst, neigh, E);
    k_final<<<NB8,256,0,stream>>>(cur, neigh, invdeg, sw, sb, n_feat, rw, (float*)d_out, N);

    (void)n_in; (void)out_size; (void)ws_size;
}

// Round 4
// 1704.878 us; speedup vs baseline: 1.3239x; 1.3239x over previous
//
#include <hip/hip_runtime.h>
#include <hip/hip_bf16.h>

typedef unsigned short u16;
typedef unsigned int   u32;
typedef __bf16 bf16x8 __attribute__((ext_vector_type(8)));
typedef float  f32x4  __attribute__((ext_vector_type(4)));

#define AS1 __attribute__((address_space(1)))
#define AS3 __attribute__((address_space(3)))

__device__ __forceinline__ u16 f2bf(float f){
    u32 u = __float_as_uint(f);
    u32 r = u + 0x7fffu + ((u>>16)&1u);
    return (u16)(r>>16);
}
__device__ __forceinline__ float bf2f(u16 u){ return __uint_as_float(((u32)u)<<16); }
// pack two fp32 -> two bf16 (truncate)
__device__ __forceinline__ u32 pack_bf(float a, float b){
    return (__float_as_uint(a)>>16) | (__float_as_uint(b) & 0xffff0000u);
}

// ---------------- degree ----------------
__global__ void k_deg(const int* __restrict__ dst, float* __restrict__ degb, int E){
    int e = blockIdx.x*256 + threadIdx.x;
    if (e < E) atomicAdd(&degb[dst[e]], 1.0f);
}

// degb -> invdeg in place; rw0 = degc^2 (so rw0*invdeg = degc = RWSE col 0)
__global__ void k_degc(float* __restrict__ invdeg, float* __restrict__ rw0, int n){
    int v = blockIdx.x*256 + threadIdx.x;
    if (v < n){
        float c = invdeg[v];
        if (c == 0.f) c = 1.f;
        invdeg[v] = 1.f/c;
        rw0[v] = c*c;
    }
}

// raw_{t+1}[dst] += (raw_t[src] * invdeg[src])
__global__ void k_rwse(const float* __restrict__ cur, float* __restrict__ nxt,
                       const float* __restrict__ invdeg, const int* __restrict__ src,
                       const int* __restrict__ dst, int E){
    int e = blockIdx.x*256 + threadIdx.x;
    if (e < E){
        int s = src[e];
        atomicAdd(&nxt[dst[e]], cur[s]*invdeg[s]);
    }
}

// out0 = relu([n_feat, rwse] @ lin0_w + lin0_b)   (fp32)
__global__ void k_finalize(const float* __restrict__ nfeat, const float* __restrict__ rw,
                           const float* __restrict__ invdeg,
                           const float* __restrict__ lw, const float* __restrict__ lb,
                           float* __restrict__ out0, int n){
    __shared__ float lwl[1024];
    __shared__ float lbl[32];
    __shared__ float nfl[8][32];
    int tid = threadIdx.x;
    for (int i = tid; i < 1024; i += 256) lwl[i] = lw[i];
    if (tid < 32) lbl[tid] = lb[tid];
    int slot = tid>>5, o = tid&31;
    int v = blockIdx.x*8 + slot;
    float nfv = 0.f;
    if (v < n){
        nfv = (o < 16) ? nfeat[(size_t)v*16 + o]
                       : rw[(size_t)(o-16)*n + v]*invdeg[v];
    }
    nfl[slot][o] = nfv;
    __syncthreads();
    if (v < n){
        float a = lbl[o];
        #pragma unroll
        for (int j = 0; j < 32; j++) a += nfl[slot][j]*lwl[j*32+o];
        out0[(size_t)v*32 + o] = a > 0.f ? a : 0.f;
    }
}

// WT[n*1024+k] = bf16(w[k*1024+n])  (fp32 -> bf16, 1024x1024)
__global__ void k_transpose(const float* __restrict__ w, u16* __restrict__ wt){
    __shared__ float t[32][33];
    int bx = blockIdx.x & 31, by = blockIdx.x >> 5;
    int x = threadIdx.x & 31, y = threadIdx.x >> 5;
    #pragma unroll
    for (int i = 0; i < 32; i += 8)
        t[y+i][x] = w[(size_t)(by*32 + y + i)*1024 + bx*32 + x];
    __syncthreads();
    #pragma unroll
    for (int i = 0; i < 32; i += 8)
        wt[(size_t)(bx*32 + y + i)*1024 + by*32 + x] = f2bf(t[x][y+i]);
}

// W = relu(A @ B + bias) * sigmoid(A @ gw + gb), natural row-major store [h*32+o].
// A fp32 (global_load_lds staged, packed to bf16 in-reg), B bf16 (pre-transposed).
// Grid swizzled so the 8 column-sibling blocks of one row panel share an XCD/L2.
__global__ __launch_bounds__(256) void k_gemm(
    const float* __restrict__ A, const u16* __restrict__ BT,
    const float* __restrict__ bias, const float* __restrict__ gw,
    const float* __restrict__ gb, u16* __restrict__ Wout, int E)
{
    __shared__ __align__(16) float lds_a[128*32];  // [kq][m] chunks of 4 floats
    __shared__ __align__(16) u16   lds_b[128*32];  // [q][n]  chunks of 8 bf16
    __shared__ float gw_lds[1024];
    __shared__ float gpart[256];
    __shared__ float gate_lds[128];

    const int tid  = threadIdx.x;
    const int wave = tid>>6, lane = tid&63;
    const int wm = wave>>1, wn = wave&1;
    const int ql = lane>>4, rl = lane&15;

    // swizzle: 8 nb-siblings of a row panel sit at ids == same value mod 8
    const int id  = blockIdx.x;
    const int xcd = id & 7;
    const int s   = id >> 3;
    const int nb  = s & 7;
    const int mb  = (s >> 3)*8 + xcd;
    const int MBtot = (E + 127) >> 7;
    if (mb >= MBtot) return;
    const int m0 = mb<<7, n0 = nb<<7;

    for (int i = tid; i < 1024; i += 256) gw_lds[i] = gw[i];

    f32x4 acc[4][4];
    #pragma unroll
    for (int i=0;i<4;i++)
    #pragma unroll
        for (int j=0;j<4;j++) acc[i][j] = (f32x4){0.f,0.f,0.f,0.f};

    float gacc = 0.f;
    const int gm = tid & 127, kq0 = (tid>>7)*4;

    for (int k0 = 0; k0 < 1024; k0 += 32){
        __syncthreads();
        // A: fp32, 1024 chunks of 16B; ci -> (m = ci&127, kq = ci>>7)
        #pragma unroll
        for (int j=0;j<4;j++){
            const int cb = j*256 + wave*64;        // wave-uniform
            const int ci = cb + lane;
            const int m  = ci & 127, kq = ci >> 7;
            int row = m0 + m; if (row >= E) row = E-1;
            const float* ga = A + (size_t)row*1024 + k0 + kq*4;
            __builtin_amdgcn_global_load_lds(
                (const AS1 void*)ga, (AS3 void*)&lds_a[cb*4], 16, 0, 0);
        }
        // B: bf16, 512 chunks of 16B; ci -> (n = ci&127, q = ci>>7)
        #pragma unroll
        for (int j=0;j<2;j++){
            const int cb = (j*4 + wave)*64;        // wave-uniform
            const int ci = cb + lane;
            const int n  = ci & 127, q = ci >> 7;
            const u16* gB = BT + (size_t)(n0 + n)*1024 + (k0 + q*8);
            __builtin_amdgcn_global_load_lds(
                (const AS1 void*)gB, (AS3 void*)&lds_b[cb*8], 16, 0, 0);
        }
        __syncthreads();

        // fused gate partial: 16 k-values per thread per step
        #pragma unroll
        for (int q=0;q<4;q++){
            f32x4 c = *(const f32x4*)&lds_a[((kq0+q)*128 + gm)*4];
            const float* g = &gw_lds[k0 + (kq0+q)*4];
            gacc += c.x*g[0] + c.y*g[1] + c.z*g[2] + c.w*g[3];
        }

        bf16x8 af[4], bfr[4];
        #pragma unroll
        for (int t=0;t<4;t++){
            const int m = wm*64 + t*16 + rl;
            f32x4 lo = *(const f32x4*)&lds_a[((ql*2    )*128 + m)*4];
            f32x4 hi = *(const f32x4*)&lds_a[((ql*2 + 1)*128 + m)*4];
            u32 pk[4] = { pack_bf(lo.x, lo.y), pack_bf(lo.z, lo.w),
                          pack_bf(hi.x, hi.y), pack_bf(hi.z, hi.w) };
            af[t]  = *(bf16x8*)pk;
            bfr[t] = *(const bf16x8*)&lds_b[(ql*128 + wn*64 + t*16 + rl)*8];
        }
        #pragma unroll
        for (int mt=0;mt<4;mt++)
        #pragma unroll
            for (int nt=0;nt<4;nt++)
                acc[mt][nt] = __builtin_amdgcn_mfma_f32_16x16x32_bf16(af[mt], bfr[nt], acc[mt][nt], 0,0,0);
    }

    gpart[tid] = gacc;
    __syncthreads();
    if (tid < 128){
        float z = gpart[tid] + gpart[tid+128] + gb[0];
        gate_lds[tid] = 1.f/(1.f + __expf(-z));
    }
    __syncthreads();

    float bcol[4];
    #pragma unroll
    for (int nt=0;nt<4;nt++) bcol[nt] = bias[n0 + wn*64 + nt*16 + rl];

    #pragma unroll
    for (int mt=0;mt<4;mt++){
        const int rloc0 = wm*64 + mt*16 + ql*4;
        #pragma unroll
        for (int r=0;r<4;r++){
            const int row = m0 + rloc0 + r;
            if (row < E){
                const float g = gate_lds[rloc0 + r];
                u16* wrow = Wout + (size_t)row*1024 + n0 + wn*64 + rl;
                #pragma unroll
                for (int nt=0;nt<4;nt++){    // consecutive nt -> adjacent 32B runs, write-combine
                    float v = acc[mt][nt][r] + bcol[nt];
                    v = v > 0.f ? v : 0.f;
                    wrow[nt*16] = f2bf(v*g);
                }
            }
        }
    }
}

// msg[e][o] = sum_h out[src[e]][h] * W[e, h*32+o]; atomic into neigh[dst]
__global__ void k_msg(const float* __restrict__ outc, const u16* __restrict__ W,
                      const int* __restrict__ src, const int* __restrict__ dst,
                      float* __restrict__ neigh, int E)
{
    __shared__ float xl[8][32];
    const int tid = threadIdx.x, slot = tid>>5, o = tid&31;
    const int e = blockIdx.x*8 + slot;
    int d = 0;
    if (e < E){
        d = dst[e];
        xl[slot][o] = outc[(size_t)src[e]*32 + o];
    }
    __syncthreads();
    if (e < E){
        const float* x = xl[slot];
        const u16* wr = W + (size_t)e*1024 + o;
        float acc = 0.f;
        #pragma unroll
        for (int h = 0; h < 32; h++)
            acc += x[h]*bf2f(wr[h*32]);
        atomicAdd(&neigh[(size_t)d*32 + o], acc);
    }
}

// m = relu(neigh*invdeg + out + cb); out_new = [m,out] @ mw + mb   (fp32)
__global__ void k_node(const float* __restrict__ neigh, const float* __restrict__ invdeg,
                       const float* __restrict__ outc, const float* __restrict__ cb,
                       const float* __restrict__ mw, const float* __restrict__ mb,
                       float* __restrict__ outn, int n)
{
    __shared__ float mwl[2048];
    __shared__ float cat[8][64];
    int tid = threadIdx.x;
    for (int i = tid; i < 2048; i += 256) mwl[i] = mw[i];
    int slot = tid>>5, o = tid&31;
    int v = blockIdx.x*8 + slot;
    if (v < n){
        float ov = outc[(size_t)v*32 + o];
        float m = neigh[(size_t)v*32 + o]*invdeg[v] + ov + cb[o];
        m = m > 0.f ? m : 0.f;
        cat[slot][o] = m;
        cat[slot][32+o] = ov;
    }
    __syncthreads();
    if (v < n){
        float a = mb[o];
        #pragma unroll
        for (int j = 0; j < 64; j++) a += cat[slot][j]*mwl[j*32+o];
        outn[(size_t)v*32 + o] = a;
    }
}

__global__ void k_group(const float* __restrict__ outc, const int* __restrict__ src,
                        const int* __restrict__ dst, float* __restrict__ grp, int E)
{
    int tid = threadIdx.x, slot = tid>>5, o = tid&31;
    int e = blockIdx.x*8 + slot;
    if (e < E)
        atomicAdd(&grp[(size_t)dst[e]*32 + o], outc[(size_t)src[e]*32 + o]);
}

// out_final = [out, group*invdeg] @ sw + sb + init  (fp32 out)
__global__ void k_final(const float* __restrict__ outc, const float* __restrict__ grp,
                        const float* __restrict__ invdeg, const float* __restrict__ sw,
                        const float* __restrict__ sb, const float* __restrict__ nfeat,
                        const float* __restrict__ rw,
                        float* __restrict__ dout, int n)
{
    __shared__ float swl[2048];
    __shared__ float cat[8][64];
    int tid = threadIdx.x;
    for (int i = tid; i < 2048; i += 256) swl[i] = sw[i];
    int slot = tid>>5, o = tid&31;
    int v = blockIdx.x*8 + slot;
    float iv = 0.f;
    if (v < n){
        iv = invdeg[v];
        cat[slot][o] = outc[(size_t)v*32 + o];
        cat[slot][32+o] = grp[(size_t)v*32 + o]*iv;
    }
    __syncthreads();
    if (v < n){
        float a = sb[o];
        #pragma unroll
        for (int j = 0; j < 64; j++) a += cat[slot][j]*swl[j*32+o];
        float initv = (o < 16) ? nfeat[(size_t)v*16 + o]
                               : rw[(size_t)(o-16)*n + v]*iv;
        dout[(size_t)v*32 + o] = a + initv;
    }
}

extern "C" void kernel_launch(void* const* d_in, const int* in_sizes, int n_in,
                              void* d_out, int out_size, void* d_ws, size_t ws_size,
                              hipStream_t stream)
{
    const float* n_feat = (const float*)d_in[0];
    const float* e_feat = (const float*)d_in[1];
    const int*   src    = (const int*)d_in[2];
    const int*   dst    = (const int*)d_in[3];
    const float* epw    = (const float*)d_in[4];
    const float* epb    = (const float*)d_in[5];
    const float* gw     = (const float*)d_in[6];
    const float* gb     = (const float*)d_in[7];
    const float* l0w    = (const float*)d_in[8];
    const float* l0b    = (const float*)d_in[9];
    const float* cb     = (const float*)d_in[10];
    const float* mw     = (const float*)d_in[11];
    const float* mbp    = (const float*)d_in[12];
    const float* sw     = (const float*)d_in[13];
    const float* sb     = (const float*)d_in[14];

    const int N = in_sizes[0] / 16;
    const int E = in_sizes[2];

    char* w = (char*)d_ws;
    float* invdeg = (float*)w;  w += (size_t)N*4;
    float* rw     = (float*)w;  w += (size_t)16*N*4;
    float* out_a  = (float*)w;  w += (size_t)32*N*4;
    float* out_b  = (float*)w;  w += (size_t)32*N*4;
    float* neigh  = (float*)w;  w += (size_t)32*N*4;
    u16*   wtb    = (u16*)w;    w += (size_t)1024*1024*2;
    u16*   wout   = (u16*)w;

    hipMemsetAsync(invdeg, 0, (size_t)N*4, stream);
    hipMemsetAsync(rw, 0, (size_t)16*N*4, stream);

    const int EB  = (E + 255)/256, NB = (N + 255)/256;
    const int EB8 = (E + 7)/8,    NB8 = (N + 7)/8;

    k_deg<<<EB,256,0,stream>>>(dst, invdeg, E);
    k_degc<<<NB,256,0,stream>>>(invdeg, rw, N);
    for (int t = 0; t < 15; t++)
        k_rwse<<<EB,256,0,stream>>>(rw + (size_t)t*N, rw + (size_t)(t+1)*N, invdeg, src, dst, E);
    k_finalize<<<NB8,256,0,stream>>>(n_feat, rw, invdeg, l0w, l0b, out_a, N);

    k_transpose<<<1024,256,0,stream>>>(epw, wtb);

    const int MBtot = (E + 127)/128;
    const int grid  = ((MBtot + 7)/8)*64;
    k_gemm<<<grid,256,0,stream>>>(e_feat, wtb, epb, gw, gb, wout, E);

    float* cur = out_a; float* nxt = out_b;
    for (int it = 0; it < 3; it++){
        hipMemsetAsync(neigh, 0, (size_t)32*N*4, stream);
        k_msg<<<EB8,256,0,stream>>>(cur, wout, src, dst, neigh, E);
        k_node<<<NB8,256,0,stream>>>(neigh, invdeg, cur, cb, mw, mbp, nxt, N);
        float* tmp = cur; cur = nxt; nxt = tmp;
    }

    hipMemsetAsync(neigh, 0, (size_t)32*N*4, stream);
    k_group<<<EB8,256,0,stream>>>(cur, src, dst, neigh, E);
    k_final<<<NB8,256,0,stream>>>(cur, neigh, invdeg, sw, sb, n_feat, rw, (float*)d_out, N);

    (void)n_in; (void)out_size; (void)ws_size;
}